// Round 3
// baseline (307.664 us; speedup 1.0000x reference)
//
#include <hip/hip_runtime.h>
#include <stdint.h>

#define D_DIM 1024
#define M_DIM 128
#define BR 32
#define BD 32
#define NCHUNK (D_DIM / BD)   // 32

// Bit-exact semantics (verified R7, absmax=0.0):
//   h[r][m]  = sequential __fmaf_rn chain over d = 0..1023 (ascending)
//   FWHT stages on column-bit 0,1,...,6 ascending; out[bit]=a+b / a-b, fp32
//   bit = (h > 0) ? 1.0f : 0.0f
//
// R10: occupancy is structurally 4 waves/CU (4096 outputs/wave), so:
//   - X bypasses LDS: each xf read is shared by 16 lanes (same trow) ->
//     global float4 load, 4 unique addrs/wave, L1-served. LDS pipe now
//     carries only 8 W ds_read_b128 per j4 (384 cyc/CU) < FMA 512 cyc.
//   - 64-thread (1-wave) blocks, BR=32, grid=1024, 4 independent
//     blocks/CU. __syncthreads() in a 1-wave block = self vmcnt drain;
//     no lockstep, stalls decorrelate across SIMDs.
//   - register pipeline: X depth-2 (xf[3] rotation), W depth-1 (wf[2]),
//     fully unrolled j4 loop -> all indices/offsets compile-time.
//   - W LDS tile [128 rows][8 chunks of 16B], chunk-swizzled via the
//     GLOBAL source: phys = cj ^ (row>>3 & 7); read applies same XOR.
//     Worst case 2 lanes/bank-quad = free (m136).

typedef const __attribute__((address_space(1))) void* gas_cptr;
typedef __attribute__((address_space(3))) void* lds_vptr;

__device__ __forceinline__ void gload_lds16(const float* g, float* l) {
    __builtin_amdgcn_global_load_lds((gas_cptr)g, (lds_vptr)l, 16, 0, 0);
}

__global__ __launch_bounds__(64, 1)
void rewa_kernel(const float* __restrict__ X, const float* __restrict__ W,
                 float* __restrict__ out) {
    #pragma clang fp contract(off)
    __shared__ float wsh[2][M_DIM * BD];   // 2 x 16 KB, chunk-swizzled

    const int lane = threadIdx.x & 63;
    const int tcol = lane & 15;            // cols 8*tcol .. 8*tcol+7
    const int trow = lane >> 4;            // rows 8*trow .. 8*trow+7
    const int swz  = tcol & 7;
    const size_t row0 = (size_t)blockIdx.x * BR;

    // W staging sources (pre-applying the inverse read swizzle).
    // instr q covers rows 8q..8q+7; lane l -> row 8q+(l>>3), phys chunk l&7,
    // so logical chunk = (l&7) ^ (q&7)  [row>>3 == q within the instr].
    const float* wsrc[16];
    #pragma unroll
    for (int q = 0; q < 16; ++q) {
        const int r  = 8 * q + (lane >> 3);
        const int cj = (lane & 7) ^ (q & 7);
        wsrc[q] = W + (size_t)r * D_DIM + 4 * cj;
    }
    // X row pointers (advanced by BD per chunk -> in-loop offsets are imm)
    const float* xrow[8];
    #pragma unroll
    for (int rr = 0; rr < 8; ++rr)
        xrow[rr] = X + (row0 + 8 * trow + rr) * D_DIM;

    float acc[8][8];   // [ci][rr]
    #pragma unroll
    for (int ci = 0; ci < 8; ++ci)
        #pragma unroll
        for (int rr = 0; rr < 8; ++rr) acc[ci][rr] = 0.0f;

    // prologue: stage chunk 0 into buffer 0
    #pragma unroll
    for (int q = 0; q < 16; ++q)
        gload_lds16(wsrc[q], &wsh[0][q * 256]);
    #pragma unroll
    for (int q = 0; q < 16; ++q) wsrc[q] += BD;

    for (int ch = 0; ch < NCHUNK; ++ch) {
        __syncthreads();               // stage(ch) landed (vmcnt drain)
        const int buf = ch & 1;
        const float* wb = &wsh[buf][0];

        float4 xf[3][8], wf[2][8];
        // pipeline prologue: X for jp=0,1; W for jp=0 — issued BEFORE the
        // next-chunk stage so their waits don't drain the stage loads.
        #pragma unroll
        for (int rr = 0; rr < 8; ++rr)
            xf[0][rr] = *(const float4*)(xrow[rr] + 0);
        #pragma unroll
        for (int rr = 0; rr < 8; ++rr)
            xf[1][rr] = *(const float4*)(xrow[rr] + 4);
        #pragma unroll
        for (int ci = 0; ci < 8; ++ci)
            wf[0][ci] = *(const float4*)&wb[(8 * tcol + ci) * BD + (swz << 2)];

        if (ch + 1 < NCHUNK) {         // stage next chunk into other buffer
            #pragma unroll
            for (int q = 0; q < 16; ++q)
                gload_lds16(wsrc[q], &wsh[buf ^ 1][q * 256]);
            #pragma unroll
            for (int q = 0; q < 16; ++q) wsrc[q] += BD;
        }

        #pragma unroll
        for (int jp = 0; jp < 8; ++jp) {
            if (jp + 2 < 8) {          // X prefetch, depth 2
                #pragma unroll
                for (int rr = 0; rr < 8; ++rr)
                    xf[(jp + 2) % 3][rr] =
                        *(const float4*)(xrow[rr] + 4 * (jp + 2));
            }
            if (jp + 1 < 8) {          // W prefetch, depth 1
                #pragma unroll
                for (int ci = 0; ci < 8; ++ci)
                    wf[(jp + 1) & 1][ci] = *(const float4*)
                        &wb[(8 * tcol + ci) * BD + (((jp + 1) ^ swz) << 2)];
            }
            // d = ch*32 + jp*4 + e, ascending (bit-exact chain order)
            #pragma unroll
            for (int e = 0; e < 4; ++e)
                #pragma unroll
                for (int rr = 0; rr < 8; ++rr) {
                    const float xv = ((const float*)&xf[jp % 3][rr])[e];
                    #pragma unroll
                    for (int ci = 0; ci < 8; ++ci)
                        acc[ci][rr] = __fmaf_rn(
                            xv, ((const float*)&wf[jp & 1][ci])[e],
                            acc[ci][rr]);
                }
        }
        #pragma unroll
        for (int rr = 0; rr < 8; ++rr) xrow[rr] += BD;
    }

    // ---- FWHT, fp32, ascending column bits. col = 8*tcol + ci ----
    // bits 0,1,2 live in ci (register butterflies, FIRST)
    #pragma unroll
    for (int rr = 0; rr < 8; ++rr) {
        const float a0 = acc[0][rr], a1 = acc[1][rr];
        const float a2 = acc[2][rr], a3 = acc[3][rr];
        const float a4 = acc[4][rr], a5 = acc[5][rr];
        const float a6 = acc[6][rr], a7 = acc[7][rr];
        // bit 0
        const float b0 = __fadd_rn(a0, a1), b1 = __fsub_rn(a0, a1);
        const float b2 = __fadd_rn(a2, a3), b3 = __fsub_rn(a2, a3);
        const float b4 = __fadd_rn(a4, a5), b5 = __fsub_rn(a4, a5);
        const float b6 = __fadd_rn(a6, a7), b7 = __fsub_rn(a6, a7);
        // bit 1
        const float c0 = __fadd_rn(b0, b2), c1 = __fadd_rn(b1, b3);
        const float c2 = __fsub_rn(b0, b2), c3 = __fsub_rn(b1, b3);
        const float c4 = __fadd_rn(b4, b6), c5 = __fadd_rn(b5, b7);
        const float c6 = __fsub_rn(b4, b6), c7 = __fsub_rn(b5, b7);
        // bit 2
        acc[0][rr] = __fadd_rn(c0, c4);
        acc[1][rr] = __fadd_rn(c1, c5);
        acc[2][rr] = __fadd_rn(c2, c6);
        acc[3][rr] = __fadd_rn(c3, c7);
        acc[4][rr] = __fsub_rn(c0, c4);
        acc[5][rr] = __fsub_rn(c1, c5);
        acc[6][rr] = __fsub_rn(c2, c6);
        acc[7][rr] = __fsub_rn(c3, c7);
    }
    // bits 3..6 live in tcol = lane bits 0..3 (lane>>4 same on both ends)
    #pragma unroll
    for (int h = 1; h <= 8; h <<= 1) {
        const bool up = (tcol & h) != 0;
        #pragma unroll
        for (int ci = 0; ci < 8; ++ci)
            #pragma unroll
            for (int rr = 0; rr < 8; ++rr) {
                const float mine  = acc[ci][rr];
                const float other = __shfl_xor(mine, h, 64);
                acc[ci][rr] = up ? __fsub_rn(other, mine)
                                 : __fadd_rn(mine, other);
            }
    }

    // sign + float4 stores (two per row, cols 8*tcol..+7)
    #pragma unroll
    for (int rr = 0; rr < 8; ++rr) {
        const size_t row = row0 + 8 * trow + rr;
        float4 v0, v1;
        v0.x = (acc[0][rr] > 0.0f) ? 1.0f : 0.0f;
        v0.y = (acc[1][rr] > 0.0f) ? 1.0f : 0.0f;
        v0.z = (acc[2][rr] > 0.0f) ? 1.0f : 0.0f;
        v0.w = (acc[3][rr] > 0.0f) ? 1.0f : 0.0f;
        v1.x = (acc[4][rr] > 0.0f) ? 1.0f : 0.0f;
        v1.y = (acc[5][rr] > 0.0f) ? 1.0f : 0.0f;
        v1.z = (acc[6][rr] > 0.0f) ? 1.0f : 0.0f;
        v1.w = (acc[7][rr] > 0.0f) ? 1.0f : 0.0f;
        *(float4*)(out + row * M_DIM + 8 * tcol)     = v0;
        *(float4*)(out + row * M_DIM + 8 * tcol + 4) = v1;
    }
}

extern "C" void kernel_launch(void* const* d_in, const int* in_sizes, int n_in,
                              void* d_out, int out_size, void* d_ws, size_t ws_size,
                              hipStream_t stream) {
    const float* x = (const float*)d_in[0];
    const float* W = (const float*)d_in[1];
    float* out = (float*)d_out;
    const int nrows = out_size / M_DIM;   // 32768

    hipLaunchKernelGGL(rewa_kernel, dim3(nrows / BR), dim3(64), 0, stream,
                       x, W, out);
}